// Round 13
// baseline (124.045 us; speedup 1.0000x reference)
//
#include <hip/hip_runtime.h>

#define DIM 256
#define EMB 128
#define HID 128
#define BB  4
#define NB  512
#define NU  512
#define PR  8      // proj: rows per block
#define DC  64     // proj: W1 d-chunk staged in LDS

// ---------------------------------------------------------------------------
// Kernel 1: projections (unchanged; ~6 us, small vs the 41-us fill floor).
// ---------------------------------------------------------------------------
__global__ __launch_bounds__(256) void proj_kernel(
    const float* __restrict__ bin, const float* __restrict__ unit,
    const float* __restrict__ W1,  const float* __restrict__ b1,
    float* __restrict__ bp, float* __restrict__ up)
{
    __shared__ float Ws[DC * HID];              // 32 KB
    __shared__ float As[PR * DIM];              // 8 KB (bin); unit uses half

    const int blk    = blockIdx.x;
    const bool isBin = (blk < (BB * NB / PR));
    const int inD    = isBin ? DIM : EMB;
    const float* src = isBin ? bin : unit;
    const int rowBase = (isBin ? blk : blk - (BB * NB / PR)) * PR;
    const float* wBase = W1 + (isBin ? 0 : DIM * HID);
    float* dst = isBin ? bp : up;

    const int t = threadIdx.x;

    {
        const float4* g4 = (const float4*)(src + (size_t)rowBase * inD);
        float4* s4 = (float4*)As;
        const int nf4 = PR * inD / 4;
        for (int i = t; i < nf4; i += 256) s4[i] = g4[i];
    }

    const int h  = t & 127;
    const int rg = t >> 7;
    float acc0 = 0.f, acc1 = 0.f, acc2 = 0.f, acc3 = 0.f;
    const float* aBase = As + (rg * 4) * inD;

    for (int d0 = 0; d0 < inD; d0 += DC) {
        __syncthreads();
        {
            const float4* g4 = (const float4*)(wBase + (size_t)d0 * HID);
            float4* s4 = (float4*)Ws;
#pragma unroll
            for (int i = 0; i < 8; ++i) s4[t + i * 256] = g4[t + i * 256];
        }
        __syncthreads();
#pragma unroll 4
        for (int dd = 0; dd < DC; dd += 4) {
            const int d = d0 + dd;
            float w0 = Ws[(dd + 0) * HID + h];
            float w1 = Ws[(dd + 1) * HID + h];
            float w2 = Ws[(dd + 2) * HID + h];
            float w3 = Ws[(dd + 3) * HID + h];
            float4 a0 = *(const float4*)&aBase[0 * inD + d];
            float4 a1 = *(const float4*)&aBase[1 * inD + d];
            float4 a2 = *(const float4*)&aBase[2 * inD + d];
            float4 a3 = *(const float4*)&aBase[3 * inD + d];
            acc0 = __builtin_fmaf(a0.x, w0, acc0);
            acc0 = __builtin_fmaf(a0.y, w1, acc0);
            acc0 = __builtin_fmaf(a0.z, w2, acc0);
            acc0 = __builtin_fmaf(a0.w, w3, acc0);
            acc1 = __builtin_fmaf(a1.x, w0, acc1);
            acc1 = __builtin_fmaf(a1.y, w1, acc1);
            acc1 = __builtin_fmaf(a1.z, w2, acc1);
            acc1 = __builtin_fmaf(a1.w, w3, acc1);
            acc2 = __builtin_fmaf(a2.x, w0, acc2);
            acc2 = __builtin_fmaf(a2.y, w1, acc2);
            acc2 = __builtin_fmaf(a2.z, w2, acc2);
            acc2 = __builtin_fmaf(a2.w, w3, acc2);
            acc3 = __builtin_fmaf(a3.x, w0, acc3);
            acc3 = __builtin_fmaf(a3.y, w1, acc3);
            acc3 = __builtin_fmaf(a3.z, w2, acc3);
            acc3 = __builtin_fmaf(a3.w, w3, acc3);
        }
    }
    const float bias = isBin ? b1[h] : 0.f;
    float* o = dst + (size_t)(rowBase + rg * 4) * HID + h;
    o[0 * HID] = acc0 + bias;
    o[1 * HID] = acc1 + bias;
    o[2 * HID] = acc2 + bias;
    o[3 * HID] = acc3 + bias;
}

// ---------------------------------------------------------------------------
// Kernel 2: out[b,n,u] = b2 + sum_h 0.5*W2[h] * g2(x),  x = bp[..h]+up[..h],
//   g2(x) = 2*gelu(x) = x + |x|*erf(|x|/sqrt2).
// WHY (round-12 evidence): doubling occupancy changed NOTHING -> head is
// LDS-pipe-bound (per-CU), dominated by the per-element LUT gather. So the
// gather is ELIMINATED: erf via Hastings 7.1.25 (err 2.5e-5 -> gelu err
// ~5e-5, better than the 64-LUT's 2e-4), sqrt2 folded into constants, no
// clamp (t->0 saturates exactly): 11 VALU + 2 trans per element, ZERO LDS
// gathers. LDS = sUp only (16384 B) -> 8 blocks/CU; TN=16 grid = 2048
// blocks = 8/CU real occupancy (r12-verified). Pipe budget per SIMD:
// VALU ~19us, trans ~14us (overlapped), LDS ~7us -> VALU-bound ~24-28us.
// ---------------------------------------------------------------------------
__global__ __launch_bounds__(256, 8) void head_kernel(
    const float* __restrict__ bp, const float* __restrict__ up,
    const float* __restrict__ W2, const float* __restrict__ b2p,
    float* __restrict__ out)
{
    __shared__ float sUp[32 * HID];             // 16384 B, [u][chunk ^ (u&7)]

    const int b  = blockIdx.z;
    const int n0 = blockIdx.y * 16;             // TN=16
    const int u0 = blockIdx.x * 32;             // TU=32
    const int t  = threadIdx.x;

    // ---- stage up tile [32][128], 16B-chunk XOR swizzle: 1024 float4
    {
        const float4* g = (const float4*)(up + ((size_t)b * NU + u0) * HID);
#pragma unroll
        for (int i = 0; i < 4; ++i) {
            int f   = i * 256 + t;
            float4 v = g[f];
            int row = f >> 5;                   // u within tile (32 f4/row)
            int st  = (f & 31) ^ (row & 7);
            *(float4*)&sUp[row * HID + st * 4] = v;
        }
    }
    __syncthreads();

    const int u    = t & 31;
    const int ng   = t >> 5;                    // n rows: ng, ng+8
    const int sswz = (u & 7) << 2;
    float acc0 = 0.f, acc1 = 0.f;
    const float* upRow = sUp + u * HID;
    const float b2 = *b2p;

    // bp rows from global (L2-resident, 2 distinct 16B lines/wave/load)
    const float* r0 = bp + ((size_t)b * NB + n0 + ng) * HID;
    const float* r1 = r0 + 8 * HID;

    // g2(x) = x + |x|*erf(|x|/sqrt2), Hastings 7.1.25 (sqrt2 pre-folded):
    //   den = 1 + 0.33267245*ax          (0.47047/sqrt2)
    //   p   = ((a3*t + a2)*t + a1)*t,  t = rcp(den)
    //   e   = exp2(-0.72134752 * ax^2)   (log2e/2)
    //   g2  = fma(ax, 1 - p*e, x)
    // 11 VALU + 2 trans, no clamp, exact saturation at |x|->inf.
#define GELU2_ACC(X, WH, A)                                     \
    {                                                           \
        float ax  = __builtin_fabsf(X);                         \
        float den = __builtin_fmaf(0.33267245f, ax, 1.0f);      \
        float tt  = __builtin_amdgcn_rcpf(den);                 \
        float pp  = __builtin_fmaf(0.7478556f, tt, -0.0958798f);\
        pp = __builtin_fmaf(pp, tt, 0.3480242f);                \
        pp = pp * tt;                                           \
        float ss  = ax * ax;                                    \
        float ee  = __builtin_amdgcn_exp2f(-0.72134752f * ss);  \
        float ef  = __builtin_fmaf(-pp, ee, 1.0f);              \
        float g2  = __builtin_fmaf(ax, ef, (X));                \
        A = __builtin_fmaf((WH), g2, A);                        \
    }

    for (int c = 0; c < 32; ++c) {
        const int h = c * 4;
        float4 uv4 = *(const float4*)&upRow[h ^ sswz];     // b128, conflict-free
        float4 w4  = *(const float4*)(W2 + h);             // uniform -> s_load
        float4 q0  = *(const float4*)&r0[h];               // VMEM, L1/L2-hit
        float4 q1  = *(const float4*)&r1[h];

#pragma unroll
        for (int j = 0; j < 4; ++j) {
            const float wh = 0.5f * (&w4.x)[j];            // fold the 1/2 here
            float x0 = (&q0.x)[j] + (&uv4.x)[j];
            GELU2_ACC(x0, wh, acc0);
            float x1 = (&q1.x)[j] + (&uv4.x)[j];
            GELU2_ACC(x1, wh, acc1);
        }
    }
#undef GELU2_ACC

    float* o = out + ((size_t)b * NB + n0 + ng) * NU + u0 + u;
    o[0]      = acc0 + b2;                      // row ng
    o[8 * NU] = acc1 + b2;                      // row ng+8
}

// ---------------------------------------------------------------------------
extern "C" void kernel_launch(void* const* d_in, const int* in_sizes, int n_in,
                              void* d_out, int out_size, void* d_ws, size_t ws_size,
                              hipStream_t stream)
{
    const float* bin  = (const float*)d_in[0];
    const float* unit = (const float*)d_in[1];
    const float* W1   = (const float*)d_in[2];
    const float* b1   = (const float*)d_in[3];
    const float* W2   = (const float*)d_in[4];
    const float* b2   = (const float*)d_in[5];
    float* out = (float*)d_out;

    float* bp = (float*)d_ws;                   // [B*NB, HID] = 1 MB
    float* up = bp + (size_t)BB * NB * HID;     // [B*NU, HID] = 1 MB

    proj_kernel<<<dim3(BB * NB / PR + BB * NU / PR), 256, 0, stream>>>(
        bin, unit, W1, b1, bp, up);
    head_kernel<<<dim3(NU / 32, NB / 16, BB), 256, 0, stream>>>(
        bp, up, W2, b2, out);
}

// Round 14
// 112.957 us; speedup vs baseline: 1.0982x; 1.0982x over previous
//
#include <hip/hip_runtime.h>

#define DIM 256
#define EMB 128
#define HID 128
#define BB  4
#define NB  512
#define NU  512
#define PR  8      // proj: rows per block
#define DC  64     // proj: W1 d-chunk staged in LDS

// ---------------------------------------------------------------------------
// Φ(x) via A&S 7.1.26 (err 1.5e-7) — LUT build only.
// ---------------------------------------------------------------------------
__device__ __forceinline__ float phi_as(float x) {
    float z = __builtin_fabsf(x) * 0.70710678118654752f;
    float t = __builtin_amdgcn_rcpf(__builtin_fmaf(0.3275911f, z, 1.0f));
    float p = __builtin_fmaf(1.061405429f, t, -1.453152027f);
    p = __builtin_fmaf(p, t, 1.421413741f);
    p = __builtin_fmaf(p, t, -0.284496736f);
    p = __builtin_fmaf(p, t, 0.254829592f);
    p = p * t;
    float e = __builtin_amdgcn_exp2f(-1.4426950408889634f * z * z);
    float erfabs = __builtin_fmaf(-p, e, 1.0f);
    return __builtin_fmaf(__builtin_copysignf(0.5f, x), erfabs, 0.5f);
}

// ---------------------------------------------------------------------------
// Kernel 1: projections (unchanged; ~6 us, small vs the 41-us fill floor).
// ---------------------------------------------------------------------------
__global__ __launch_bounds__(256) void proj_kernel(
    const float* __restrict__ bin, const float* __restrict__ unit,
    const float* __restrict__ W1,  const float* __restrict__ b1,
    float* __restrict__ bp, float* __restrict__ up)
{
    __shared__ float Ws[DC * HID];              // 32 KB
    __shared__ float As[PR * DIM];              // 8 KB (bin); unit uses half

    const int blk    = blockIdx.x;
    const bool isBin = (blk < (BB * NB / PR));
    const int inD    = isBin ? DIM : EMB;
    const float* src = isBin ? bin : unit;
    const int rowBase = (isBin ? blk : blk - (BB * NB / PR)) * PR;
    const float* wBase = W1 + (isBin ? 0 : DIM * HID);
    float* dst = isBin ? bp : up;

    const int t = threadIdx.x;

    {
        const float4* g4 = (const float4*)(src + (size_t)rowBase * inD);
        float4* s4 = (float4*)As;
        const int nf4 = PR * inD / 4;
        for (int i = t; i < nf4; i += 256) s4[i] = g4[i];
    }

    const int h  = t & 127;
    const int rg = t >> 7;
    float acc0 = 0.f, acc1 = 0.f, acc2 = 0.f, acc3 = 0.f;
    const float* aBase = As + (rg * 4) * inD;

    for (int d0 = 0; d0 < inD; d0 += DC) {
        __syncthreads();
        {
            const float4* g4 = (const float4*)(wBase + (size_t)d0 * HID);
            float4* s4 = (float4*)Ws;
#pragma unroll
            for (int i = 0; i < 8; ++i) s4[t + i * 256] = g4[t + i * 256];
        }
        __syncthreads();
#pragma unroll 4
        for (int dd = 0; dd < DC; dd += 4) {
            const int d = d0 + dd;
            float w0 = Ws[(dd + 0) * HID + h];
            float w1 = Ws[(dd + 1) * HID + h];
            float w2 = Ws[(dd + 2) * HID + h];
            float w3 = Ws[(dd + 3) * HID + h];
            float4 a0 = *(const float4*)&aBase[0 * inD + d];
            float4 a1 = *(const float4*)&aBase[1 * inD + d];
            float4 a2 = *(const float4*)&aBase[2 * inD + d];
            float4 a3 = *(const float4*)&aBase[3 * inD + d];
            acc0 = __builtin_fmaf(a0.x, w0, acc0);
            acc0 = __builtin_fmaf(a0.y, w1, acc0);
            acc0 = __builtin_fmaf(a0.z, w2, acc0);
            acc0 = __builtin_fmaf(a0.w, w3, acc0);
            acc1 = __builtin_fmaf(a1.x, w0, acc1);
            acc1 = __builtin_fmaf(a1.y, w1, acc1);
            acc1 = __builtin_fmaf(a1.z, w2, acc1);
            acc1 = __builtin_fmaf(a1.w, w3, acc1);
            acc2 = __builtin_fmaf(a2.x, w0, acc2);
            acc2 = __builtin_fmaf(a2.y, w1, acc2);
            acc2 = __builtin_fmaf(a2.z, w2, acc2);
            acc2 = __builtin_fmaf(a2.w, w3, acc2);
            acc3 = __builtin_fmaf(a3.x, w0, acc3);
            acc3 = __builtin_fmaf(a3.y, w1, acc3);
            acc3 = __builtin_fmaf(a3.z, w2, acc3);
            acc3 = __builtin_fmaf(a3.w, w3, acc3);
        }
    }
    const float bias = isBin ? b1[h] : 0.f;
    float* o = dst + (size_t)(rowBase + rg * 4) * HID + h;
    o[0 * HID] = acc0 + bias;
    o[1 * HID] = acc1 + bias;
    o[2 * HID] = acc2 + bias;
    o[3 * HID] = acc3 + bias;
}

// ---------------------------------------------------------------------------
// Kernel 2: out = b2 + 0.5 * sum_h W2[h] * g2(x),  g2 = 2*gelu, x = bp+up.
// HYBRID (r12+r13 measured): full-LUT saturates the per-CU LDS pipe at
// ~34us (occupancy-invariant, r12); full-arith costs 51 VALU-cyc/elem
// (trans = 16 cyc each in the issue stream, r13). These are DIFFERENT
// pipes -> statically route 5 of 8 elems/iter through the 64-entry g2-LUT
// gather (LDS) and 3 of 8 through Hastings erf (VALU+trans), balancing
// LDS ~21us/CU vs VALU ~25us/SIMD. 0.5 folded into the epilogue (no
// per-elem wh mul). LDS = sUp 16K + LUT 512B = 16896 B -> 8 blocks/CU;
// grid 2048 = 8/CU real (r12-verified); launch_bounds(256,8).
// ---------------------------------------------------------------------------
__global__ __launch_bounds__(256, 8) void head_kernel(
    const float* __restrict__ bp, const float* __restrict__ up,
    const float* __restrict__ W2, const float* __restrict__ b2p,
    float* __restrict__ out)
{
    __shared__ float sUp[32 * HID];             // 16384 B, [u][chunk ^ (u&7)]
    __shared__ float sLut[128];                 // 512 B: 64 x (y=g2, dy)

    const int b  = blockIdx.z;
    const int n0 = blockIdx.y * 16;             // TN=16
    const int u0 = blockIdx.x * 32;             // TU=32
    const int t  = threadIdx.x;

    // ---- build g2 LUT: 64 entries, step 1/8 over [-4, 4); y = 2*gelu
    if (t < 64) {
        float x0 = __builtin_fmaf((float)t, 0.125f, -4.0f);
        float x1 = x0 + 0.125f;
        float y0 = 2.0f * x0 * phi_as(x0);
        float y1 = 2.0f * x1 * phi_as(x1);
        sLut[2 * t]     = y0;
        sLut[2 * t + 1] = y1 - y0;              // exact secant slope
    }

    // ---- stage up tile [32][128], 16B-chunk XOR swizzle: 1024 float4
    {
        const float4* g = (const float4*)(up + ((size_t)b * NU + u0) * HID);
#pragma unroll
        for (int i = 0; i < 4; ++i) {
            int f   = i * 256 + t;
            float4 v = g[f];
            int row = f >> 5;                   // u within tile (32 f4/row)
            int st  = (f & 31) ^ (row & 7);
            *(float4*)&sUp[row * HID + st * 4] = v;
        }
    }
    __syncthreads();

    const int u    = t & 31;
    const int ng   = t >> 5;                    // n rows: ng, ng+8
    const int sswz = (u & 7) << 2;
    float acc0 = 0.f, acc1 = 0.f;
    const float* upRow = sUp + u * HID;
    const float b2 = *b2p;

    // bp rows from global (L2-resident, 2 distinct 16B lines/wave/load)
    const float* r0 = bp + ((size_t)b * NB + n0 + ng) * HID;
    const float* r1 = r0 + 8 * HID;

    // LUT path: med3, fma(idx), cvt, fract, ds_read_b64 gather, interp-fma
#define G2_LUT(X, W, A)                                         \
    {                                                           \
        float xc = __builtin_amdgcn_fmed3f((X), -4.0f, 3.9921875f); \
        float ff = __builtin_fmaf(xc, 8.0f, 32.0f);             \
        unsigned ii = (unsigned)ff;                             \
        float fr = __builtin_amdgcn_fractf(ff);                 \
        float2 yd = *(const float2*)&sLut[ii * 2];              \
        float g2 = __builtin_fmaf(fr, yd.y, yd.x);              \
        A = __builtin_fmaf((W), g2, A);                         \
    }
    // Arith path (r13-validated): Hastings 7.1.25, sqrt2 folded; 2 trans.
#define G2_ARITH(X, W, A)                                       \
    {                                                           \
        float ax  = __builtin_fabsf(X);                         \
        float den = __builtin_fmaf(0.33267245f, ax, 1.0f);      \
        float tt  = __builtin_amdgcn_rcpf(den);                 \
        float pp  = __builtin_fmaf(0.7478556f, tt, -0.0958798f);\
        pp = __builtin_fmaf(pp, tt, 0.3480242f);                \
        pp = pp * tt;                                           \
        float ss  = ax * ax;                                    \
        float ee  = __builtin_amdgcn_exp2f(-0.72134752f * ss);  \
        float ef  = __builtin_fmaf(-pp, ee, 1.0f);              \
        float g2  = __builtin_fmaf(ax, ef, (X));                \
        A = __builtin_fmaf((W), g2, A);                         \
    }

    for (int c = 0; c < 32; ++c) {
        const int h = c * 4;
        float4 uv4 = *(const float4*)&upRow[h ^ sswz];     // b128, conflict-free
        float4 w4  = *(const float4*)(W2 + h);             // uniform -> s_load
        float4 q0  = *(const float4*)&r0[h];               // VMEM, L1/L2-hit
        float4 q1  = *(const float4*)&r1[h];

        // 8 elems: 5 via LUT (LDS pipe), 3 via arith (VALU+trans pipe)
        float x;
        x = q0.x + uv4.x; G2_LUT  (x, w4.x, acc0);
        x = q1.x + uv4.x; G2_LUT  (x, w4.x, acc1);
        x = q0.y + uv4.y; G2_LUT  (x, w4.y, acc0);
        x = q1.y + uv4.y; G2_LUT  (x, w4.y, acc1);
        x = q0.z + uv4.z; G2_LUT  (x, w4.z, acc0);
        x = q1.z + uv4.z; G2_ARITH(x, w4.z, acc1);
        x = q0.w + uv4.w; G2_ARITH(x, w4.w, acc0);
        x = q1.w + uv4.w; G2_ARITH(x, w4.w, acc1);
    }
#undef G2_LUT
#undef G2_ARITH

    float* o = out + ((size_t)b * NB + n0 + ng) * NU + u0 + u;
    o[0]      = __builtin_fmaf(0.5f, acc0, b2);   // row ng
    o[8 * NU] = __builtin_fmaf(0.5f, acc1, b2);   // row ng+8
}

// ---------------------------------------------------------------------------
extern "C" void kernel_launch(void* const* d_in, const int* in_sizes, int n_in,
                              void* d_out, int out_size, void* d_ws, size_t ws_size,
                              hipStream_t stream)
{
    const float* bin  = (const float*)d_in[0];
    const float* unit = (const float*)d_in[1];
    const float* W1   = (const float*)d_in[2];
    const float* b1   = (const float*)d_in[3];
    const float* W2   = (const float*)d_in[4];
    const float* b2   = (const float*)d_in[5];
    float* out = (float*)d_out;

    float* bp = (float*)d_ws;                   // [B*NB, HID] = 1 MB
    float* up = bp + (size_t)BB * NB * HID;     // [B*NU, HID] = 1 MB

    proj_kernel<<<dim3(BB * NB / PR + BB * NU / PR), 256, 0, stream>>>(
        bin, unit, W1, b1, bp, up);
    head_kernel<<<dim3(NU / 32, NB / 16, BB), 256, 0, stream>>>(
        bp, up, W2, b2, out);
}

// Round 15
// 105.690 us; speedup vs baseline: 1.1737x; 1.0688x over previous
//
#include <hip/hip_runtime.h>

#define DIM 256
#define EMB 128
#define HID 128
#define BB  4
#define NB  512
#define NU  512
#define PR  8      // proj: rows per block
#define DC  64     // proj: W1 d-chunk staged in LDS

typedef float f2 __attribute__((ext_vector_type(2)));

// ---------------------------------------------------------------------------
// Φ(x) via A&S 7.1.26 (err 1.5e-7) — LUT build only.
// ---------------------------------------------------------------------------
__device__ __forceinline__ float phi_as(float x) {
    float z = __builtin_fabsf(x) * 0.70710678118654752f;
    float t = __builtin_amdgcn_rcpf(__builtin_fmaf(0.3275911f, z, 1.0f));
    float p = __builtin_fmaf(1.061405429f, t, -1.453152027f);
    p = __builtin_fmaf(p, t, 1.421413741f);
    p = __builtin_fmaf(p, t, -0.284496736f);
    p = __builtin_fmaf(p, t, 0.254829592f);
    p = p * t;
    float e = __builtin_amdgcn_exp2f(-1.4426950408889634f * z * z);
    float erfabs = __builtin_fmaf(-p, e, 1.0f);
    return __builtin_fmaf(__builtin_copysignf(0.5f, x), erfabs, 0.5f);
}

// ---------------------------------------------------------------------------
// Kernel 1: projections (unchanged; ~6 us).
// ---------------------------------------------------------------------------
__global__ __launch_bounds__(256) void proj_kernel(
    const float* __restrict__ bin, const float* __restrict__ unit,
    const float* __restrict__ W1,  const float* __restrict__ b1,
    float* __restrict__ bp, float* __restrict__ up)
{
    __shared__ float Ws[DC * HID];              // 32 KB
    __shared__ float As[PR * DIM];              // 8 KB (bin); unit uses half

    const int blk    = blockIdx.x;
    const bool isBin = (blk < (BB * NB / PR));
    const int inD    = isBin ? DIM : EMB;
    const float* src = isBin ? bin : unit;
    const int rowBase = (isBin ? blk : blk - (BB * NB / PR)) * PR;
    const float* wBase = W1 + (isBin ? 0 : DIM * HID);
    float* dst = isBin ? bp : up;

    const int t = threadIdx.x;

    {
        const float4* g4 = (const float4*)(src + (size_t)rowBase * inD);
        float4* s4 = (float4*)As;
        const int nf4 = PR * inD / 4;
        for (int i = t; i < nf4; i += 256) s4[i] = g4[i];
    }

    const int h  = t & 127;
    const int rg = t >> 7;
    float acc0 = 0.f, acc1 = 0.f, acc2 = 0.f, acc3 = 0.f;
    const float* aBase = As + (rg * 4) * inD;

    for (int d0 = 0; d0 < inD; d0 += DC) {
        __syncthreads();
        {
            const float4* g4 = (const float4*)(wBase + (size_t)d0 * HID);
            float4* s4 = (float4*)Ws;
#pragma unroll
            for (int i = 0; i < 8; ++i) s4[t + i * 256] = g4[t + i * 256];
        }
        __syncthreads();
#pragma unroll 4
        for (int dd = 0; dd < DC; dd += 4) {
            const int d = d0 + dd;
            float w0 = Ws[(dd + 0) * HID + h];
            float w1 = Ws[(dd + 1) * HID + h];
            float w2 = Ws[(dd + 2) * HID + h];
            float w3 = Ws[(dd + 3) * HID + h];
            float4 a0 = *(const float4*)&aBase[0 * inD + d];
            float4 a1 = *(const float4*)&aBase[1 * inD + d];
            float4 a2 = *(const float4*)&aBase[2 * inD + d];
            float4 a3 = *(const float4*)&aBase[3 * inD + d];
            acc0 = __builtin_fmaf(a0.x, w0, acc0);
            acc0 = __builtin_fmaf(a0.y, w1, acc0);
            acc0 = __builtin_fmaf(a0.z, w2, acc0);
            acc0 = __builtin_fmaf(a0.w, w3, acc0);
            acc1 = __builtin_fmaf(a1.x, w0, acc1);
            acc1 = __builtin_fmaf(a1.y, w1, acc1);
            acc1 = __builtin_fmaf(a1.z, w2, acc1);
            acc1 = __builtin_fmaf(a1.w, w3, acc1);
            acc2 = __builtin_fmaf(a2.x, w0, acc2);
            acc2 = __builtin_fmaf(a2.y, w1, acc2);
            acc2 = __builtin_fmaf(a2.z, w2, acc2);
            acc2 = __builtin_fmaf(a2.w, w3, acc2);
            acc3 = __builtin_fmaf(a3.x, w0, acc3);
            acc3 = __builtin_fmaf(a3.y, w1, acc3);
            acc3 = __builtin_fmaf(a3.z, w2, acc3);
            acc3 = __builtin_fmaf(a3.w, w3, acc3);
        }
    }
    const float bias = isBin ? b1[h] : 0.f;
    float* o = dst + (size_t)(rowBase + rg * 4) * HID + h;
    o[0 * HID] = acc0 + bias;
    o[1 * HID] = acc1 + bias;
    o[2 * HID] = acc2 + bias;
    o[3 * HID] = acc3 + bias;
}

// ---------------------------------------------------------------------------
// Kernel 2: out = b2 + 0.5 * sum_h W2[h] * g2(x),  g2 = 2*gelu, x = bp+up.
// PURE LUT (r14 showed the Hastings lanes drag VALU to 34us + 11us of
// trans-chain stalls; pure-LUT ~38us is the better base). The r9/r14 gap
// to the ~22-24us pipe budget is UNCOVERED ~120-cyc gather latency: the
// compiler schedules gathers one-per-use (VGPR stayed 24-52). This round
// FORCES an 8-deep batch: 8 volatile ds_read_b64 issued back-to-back,
// one s_waitcnt lgkmcnt(0) + sched_barrier(0) (hipcc hoists consumers
// past inline-asm waits otherwise), then 8 interp+acc. Batch regs
// (16 VGPR yd + 8 fr + 8 addr) must appear in VGPR_Count (~48-60) —
// that's the mechanism check.
// LDS = sUp 16K + LUT 512B = 16896 B -> 8 blocks/CU; grid 2048 = 8/CU
// (r12/r14-verified 47% occupancy); launch_bounds(256,8).
// ---------------------------------------------------------------------------
__global__ __launch_bounds__(256, 8) void head_kernel(
    const float* __restrict__ bp, const float* __restrict__ up,
    const float* __restrict__ W2, const float* __restrict__ b2p,
    float* __restrict__ out)
{
    __shared__ float sUp[32 * HID];             // 16384 B, [u][chunk ^ (u&7)]
    __shared__ float sLut[128];                 // 512 B: 64 x (y=g2, dy)

    const int b  = blockIdx.z;
    const int n0 = blockIdx.y * 16;             // TN=16
    const int u0 = blockIdx.x * 32;             // TU=32
    const int t  = threadIdx.x;

    // ---- build g2 LUT: 64 entries, step 1/8 over [-4, 4); y = 2*gelu
    if (t < 64) {
        float x0 = __builtin_fmaf((float)t, 0.125f, -4.0f);
        float x1 = x0 + 0.125f;
        float y0 = 2.0f * x0 * phi_as(x0);
        float y1 = 2.0f * x1 * phi_as(x1);
        sLut[2 * t]     = y0;
        sLut[2 * t + 1] = y1 - y0;              // exact secant slope
    }

    // ---- stage up tile [32][128], 16B-chunk XOR swizzle: 1024 float4
    {
        const float4* g = (const float4*)(up + ((size_t)b * NU + u0) * HID);
#pragma unroll
        for (int i = 0; i < 4; ++i) {
            int f   = i * 256 + t;
            float4 v = g[f];
            int row = f >> 5;                   // u within tile (32 f4/row)
            int st  = (f & 31) ^ (row & 7);
            *(float4*)&sUp[row * HID + st * 4] = v;
        }
    }
    __syncthreads();

    const int u    = t & 31;
    const int ng   = t >> 5;                    // n rows: ng, ng+8
    const int sswz = (u & 7) << 2;
    float acc0 = 0.f, acc1 = 0.f;
    const float* upRow = sUp + u * HID;
    const float b2 = *b2p;

    // bp rows from global (L2-resident, 2 distinct 16B lines/wave/load)
    const float* r0 = bp + ((size_t)b * NB + n0 + ng) * HID;
    const float* r1 = r0 + 8 * HID;

    for (int c = 0; c < 32; ++c) {
        const int h = c * 4;
        float4 uv4 = *(const float4*)&upRow[h ^ sswz];     // b128, conflict-free
        float4 w4  = *(const float4*)(W2 + h);             // uniform -> s_load
        float4 q0  = *(const float4*)&r0[h];               // VMEM, L1/L2-hit
        float4 q1  = *(const float4*)&r1[h];

        // phase A: 8x {add, med3, fma(idx), cvt, fract, addr}
        float    fr[8];
        unsigned ad[8];
#pragma unroll
        for (int k = 0; k < 8; ++k) {
            float x  = (k < 4 ? (&q0.x)[k] : (&q1.x)[k - 4]) + (&uv4.x)[k & 3];
            float xc = __builtin_amdgcn_fmed3f(x, -4.0f, 3.9921875f);
            float ff = __builtin_fmaf(xc, 8.0f, 32.0f);
            unsigned ii = (unsigned)ff;                    // trunc==floor (ff>=0)
            fr[k] = __builtin_amdgcn_fractf(ff);
            ad[k] = (unsigned)(unsigned long)&sLut[2 * ii];
        }
        // phase B: force 8 gathers in flight (volatile order), single drain
        f2 yd[8];
#pragma unroll
        for (int k = 0; k < 8; ++k)
            asm volatile("ds_read_b64 %0, %1" : "=v"(yd[k]) : "v"(ad[k]));
        asm volatile("s_waitcnt lgkmcnt(0)");
        __builtin_amdgcn_sched_barrier(0);                 // rule #18 fence
        // phase C: 8x {interp-fma, acc-fma}
#pragma unroll
        for (int k = 0; k < 8; ++k) {
            float g2 = __builtin_fmaf(fr[k], yd[k].y, yd[k].x);
            if (k < 4) acc0 = __builtin_fmaf((&w4.x)[k],     g2, acc0);
            else       acc1 = __builtin_fmaf((&w4.x)[k - 4], g2, acc1);
        }
    }

    float* o = out + ((size_t)b * NB + n0 + ng) * NU + u0 + u;
    o[0]      = __builtin_fmaf(0.5f, acc0, b2);   // row ng
    o[8 * NU] = __builtin_fmaf(0.5f, acc1, b2);   // row ng+8
}

// ---------------------------------------------------------------------------
extern "C" void kernel_launch(void* const* d_in, const int* in_sizes, int n_in,
                              void* d_out, int out_size, void* d_ws, size_t ws_size,
                              hipStream_t stream)
{
    const float* bin  = (const float*)d_in[0];
    const float* unit = (const float*)d_in[1];
    const float* W1   = (const float*)d_in[2];
    const float* b1   = (const float*)d_in[3];
    const float* W2   = (const float*)d_in[4];
    const float* b2   = (const float*)d_in[5];
    float* out = (float*)d_out;

    float* bp = (float*)d_ws;                   // [B*NB, HID] = 1 MB
    float* up = bp + (size_t)BB * NB * HID;     // [B*NU, HID] = 1 MB

    proj_kernel<<<dim3(BB * NB / PR + BB * NU / PR), 256, 0, stream>>>(
        bin, unit, W1, b1, bp, up);
    head_kernel<<<dim3(NU / 32, NB / 16, BB), 256, 0, stream>>>(
        bp, up, W2, b2, out);
}